// Round 3
// baseline (328.465 us; speedup 1.0000x reference)
//
#include <hip/hip_runtime.h>
#include <hip/hip_bf16.h>
#include <stdint.h>

#define Bb 8
#define Ss 1024
#define Dd 768
#define Hh 12
#define DH 64

typedef __attribute__((ext_vector_type(8))) short bf16x8;
typedef __attribute__((ext_vector_type(4))) float f32x4;

static __device__ __forceinline__ unsigned short f2b(float x) {
    union { float f; unsigned u; } v; v.f = x;
    unsigned r = v.u + 0x7FFFu + ((v.u >> 16) & 1u);
    return (unsigned short)(r >> 16);
}

static __device__ __forceinline__ void gll16(const void* g, void* l) {
    __builtin_amdgcn_global_load_lds((const __attribute__((address_space(1))) void*)g,
                                     (__attribute__((address_space(3))) void*)l,
                                     16, 0, 0);
}

// ---------------- kernel 1: hidden f32 -> bf16 ----------------
__global__ __launch_bounds__(256) void k_cvt(const float* __restrict__ in,
                                             unsigned short* __restrict__ out) {
    int i = (blockIdx.x * 256 + threadIdx.x) * 4;
    const float4 v = *reinterpret_cast<const float4*>(in + i);
    ushort4 o;
    o.x = f2b(v.x); o.y = f2b(v.y); o.z = f2b(v.z); o.w = f2b(v.w);
    *reinterpret_cast<ushort4*>(out + i) = o;
}

// ---------------- kernel 2: W[k][n] f32 -> Wt[w][n][k] bf16 ----------------
__global__ __launch_bounds__(256) void k_twt(const float* __restrict__ Wq,
                                             const float* __restrict__ Wk,
                                             const float* __restrict__ Wv,
                                             unsigned short* __restrict__ Wt) {
    __shared__ float tile[32][33];
    const int w = blockIdx.z;
    const float* W = (w == 0) ? Wq : (w == 1) ? Wk : Wv;
    const int k0 = blockIdx.x * 32, n0 = blockIdx.y * 32;
    const int c = threadIdx.x & 31, r0 = threadIdx.x >> 5;
    #pragma unroll
    for (int i = 0; i < 4; ++i)
        tile[r0 + i * 8][c] = W[(size_t)(k0 + r0 + i * 8) * Dd + n0 + c];
    __syncthreads();
    unsigned short* o = Wt + (size_t)w * Dd * Dd;
    #pragma unroll
    for (int i = 0; i < 4; ++i)
        o[(size_t)(n0 + r0 + i * 8) * Dd + k0 + c] = f2b(tile[c][r0 + i * 8]);
}

// ---------------- kernel 3: QKV GEMM (m97 structure) ----------------
__global__ __launch_bounds__(256) void k_qkv(
    const unsigned short* __restrict__ hb,   // [8192][768] bf16
    const unsigned short* __restrict__ Wt,   // [3][768][768] bf16 (n,k)
    const float* __restrict__ bq, const float* __restrict__ bk, const float* __restrict__ bv,
    unsigned short* __restrict__ Qo, unsigned short* __restrict__ Ko,
    unsigned short* __restrict__ Vo) {
    __shared__ __align__(16) unsigned short Al[128 * 32];
    __shared__ __align__(16) unsigned short Bl[128 * 32];
    const int m0 = blockIdx.x * 128;
    const int n0 = blockIdx.y * 128;
    const int w  = blockIdx.z;
    const int tid = threadIdx.x, lane = tid & 63, wv = tid >> 6;
    const int l15 = lane & 15, l4 = lane >> 4;
    const int wm = (wv >> 1) * 64, wn = (wv & 1) * 64;
    const unsigned short* Wb = Wt + (size_t)w * Dd * Dd;

    f32x4 acc[4][4];
    #pragma unroll
    for (int i = 0; i < 4; ++i)
        #pragma unroll
        for (int j = 0; j < 4; ++j)
            acc[i][j] = f32x4{0.f, 0.f, 0.f, 0.f};

    const int ldr = lane >> 2;
    const int ldc = (lane & 3) * 8;

    for (int kt = 0; kt < Dd / 32; ++kt) {
        const int k0 = kt * 32;
        #pragma unroll
        for (int i = 0; i < 2; ++i) {
            const int c = wv * 2 + i;
            gll16(hb + (size_t)(m0 + c * 16 + ldr) * Dd + k0 + ldc, Al + c * 512);
            gll16(Wb + (size_t)(n0 + c * 16 + ldr) * Dd + k0 + ldc, Bl + c * 512);
        }
        __syncthreads();
        bf16x8 af[4], bfr[4];
        #pragma unroll
        for (int i = 0; i < 4; ++i) {
            af[i]  = *reinterpret_cast<const bf16x8*>(Al + (wm + i * 16 + l15) * 32 + l4 * 8);
            bfr[i] = *reinterpret_cast<const bf16x8*>(Bl + (wn + i * 16 + l15) * 32 + l4 * 8);
        }
        #pragma unroll
        for (int i = 0; i < 4; ++i)
            #pragma unroll
            for (int j = 0; j < 4; ++j)
                acc[i][j] = __builtin_amdgcn_mfma_f32_16x16x32_bf16(af[i], bfr[j], acc[i][j], 0, 0, 0);
        __syncthreads();
    }

    const float* bias = (w == 0) ? bq : (w == 1) ? bk : bv;
    if (w < 2) {
        unsigned short* O = (w == 0) ? Qo : Ko;
        #pragma unroll
        for (int j = 0; j < 4; ++j) {
            const int n = n0 + wn + j * 16 + l15;
            const float bs = bias[n];
            const int hh = n >> 6, d = n & 63;
            #pragma unroll
            for (int i = 0; i < 4; ++i) {
                const int mb = m0 + wm + i * 16 + l4 * 4;
                #pragma unroll
                for (int r = 0; r < 4; ++r) {
                    const int m = mb + r;
                    const int b = m >> 10, s = m & 1023;
                    O[(((size_t)b * Hh + hh) * Ss + s) * DH + d] = f2b(acc[i][j][r] + bs);
                }
            }
        }
    } else {
        #pragma unroll
        for (int j = 0; j < 4; ++j) {
            const int n = n0 + wn + j * 16 + l15;
            const float bs = bias[n];
            const int hh = n >> 6, d = n & 63;
            #pragma unroll
            for (int i = 0; i < 4; ++i) {
                const int m = m0 + wm + i * 16 + l4 * 4;
                const int b = m >> 10, s = m & 1023;
                ushort4 o;
                o.x = f2b(acc[i][j][0] + bs);
                o.y = f2b(acc[i][j][1] + bs);
                o.z = f2b(acc[i][j][2] + bs);
                o.w = f2b(acc[i][j][3] + bs);
                *reinterpret_cast<ushort4*>(Vo + (((size_t)b * Hh + hh) * DH + d) * Ss + s) = o;
            }
        }
    }
}

// ---------------- kernel 4: flash attention (barrier-free, direct L2 K/V) ----------------
// Swapped QK^T: mfma(K,Q) -> lane holds 16 scores of q-row (l15).
// K/V fragments loaded straight from global (L2-resident), no K/V LDS staging.
__global__ __launch_bounds__(256) void k_attn(
    const unsigned short* __restrict__ Q,   // [96][1024][64]
    const unsigned short* __restrict__ K,   // [96][1024][64]
    const unsigned short* __restrict__ VT,  // [96][64][1024]
    const float* __restrict__ mask,         // [8][1024]
    float* __restrict__ out) {              // [8][1024][768]
    __shared__ __align__(16) float Ml[1024];          // mask * log2e
    __shared__ __align__(16) unsigned short Pl[4][16][72];
    const int qt = blockIdx.x;   // fast axis: 16 q-tiles share one head's K/V in L2
    const int bh = blockIdx.y;
    const int b = bh / Hh, h = bh % Hh;
    const int tid = threadIdx.x, lane = tid & 63, wv = tid >> 6;
    const int l15 = lane & 15, l4 = lane >> 4;
    const int q0 = qt * 64 + wv * 16;

    const unsigned short* Qb = Q + (size_t)bh * Ss * DH;
    const unsigned short* Kb = K + (size_t)bh * Ss * DH;
    const unsigned short* Vb = VT + (size_t)bh * DH * Ss;
    const float* mb = mask + (size_t)b * Ss;

    {   // stage mask row, pre-scaled to log2 domain
        const float4 mv = *reinterpret_cast<const float4*>(mb + tid * 4);
        float4 ms;
        ms.x = mv.x * 1.44269504f; ms.y = mv.y * 1.44269504f;
        ms.z = mv.z * 1.44269504f; ms.w = mv.w * 1.44269504f;
        *reinterpret_cast<float4*>(&Ml[tid * 4]) = ms;
    }
    __syncthreads();   // only barrier in the kernel

    const bf16x8 qf0 = *reinterpret_cast<const bf16x8*>(Qb + (q0 + l15) * DH + l4 * 8);
    const bf16x8 qf1 = *reinterpret_cast<const bf16x8*>(Qb + (q0 + l15) * DH + 32 + l4 * 8);

    float m2 = -3.0e38f, lsum = 0.f;   // stats for q-row = l15 (log2 domain)
    f32x4 oacc[4];
    #pragma unroll
    for (int dt = 0; dt < 4; ++dt) oacc[dt] = f32x4{0.f, 0.f, 0.f, 0.f};

    const float C1 = 0.125f * 1.44269504f;   // score scale folded into log2 domain

    for (int kt = 0; kt < Ss / 64; ++kt) {
        const unsigned short* Kt = Kb + (size_t)kt * 64 * DH;
        // ---- QK^T (swapped): sc[ct][r] = S[k = kt*64+ct*16+l4*4+r][q = q0+l15]
        f32x4 sc[4];
        #pragma unroll
        for (int ct = 0; ct < 4; ++ct) {
            const bf16x8 kf0 = *reinterpret_cast<const bf16x8*>(Kt + (ct * 16 + l15) * DH + l4 * 8);
            const bf16x8 kf1 = *reinterpret_cast<const bf16x8*>(Kt + (ct * 16 + l15) * DH + 32 + l4 * 8);
            f32x4 a = f32x4{0.f, 0.f, 0.f, 0.f};
            a = __builtin_amdgcn_mfma_f32_16x16x32_bf16(kf0, qf0, a, 0, 0, 0);
            a = __builtin_amdgcn_mfma_f32_16x16x32_bf16(kf1, qf1, a, 0, 0, 0);
            sc[ct] = a;
        }

        // ---- mask tile (broadcast LDS reads, conflict-free)
        float4 mk[4];
        #pragma unroll
        for (int ct = 0; ct < 4; ++ct)
            mk[ct] = *reinterpret_cast<const float4*>(&Ml[kt * 64 + ct * 16 + l4 * 4]);

        // ---- scores -> p (log2 domain), row max
        float p[16];
        float pmax = -3.0e38f;
        const bool dk = (kt == qt);
        #pragma unroll
        for (int ct = 0; ct < 4; ++ct) {
            const float* mkp = reinterpret_cast<const float*>(&mk[ct]);
            #pragma unroll
            for (int r = 0; r < 4; ++r) {
                float t = fmaf(sc[ct][r], C1, mkp[r]);
                if (dk && (ct * 16 + l4 * 4 + r) == (wv * 16 + l15)) t = mkp[r];  // blind spot
                p[ct * 4 + r] = t;
                pmax = fmaxf(pmax, t);
            }
        }
        pmax = fmaxf(pmax, __shfl_xor(pmax, 16));
        pmax = fmaxf(pmax, __shfl_xor(pmax, 32));

        // ---- defer-max (T13): rescale only when max grew past threshold
        if (__any(pmax > m2 + 10.f)) {
            const float mnew = fmaxf(m2, pmax);
            const float alpha = __builtin_amdgcn_exp2f(m2 - mnew);
            m2 = mnew;
            lsum *= alpha;
            float ar[4];
            #pragma unroll
            for (int r = 0; r < 4; ++r) ar[r] = __shfl(alpha, l4 * 4 + r);
            #pragma unroll
            for (int dt = 0; dt < 4; ++dt)
                #pragma unroll
                for (int r = 0; r < 4; ++r) oacc[dt][r] *= ar[r];
        }

        // ---- exp2 + row sum
        float rs = 0.f;
        #pragma unroll
        for (int i = 0; i < 16; ++i) {
            const float e = __builtin_amdgcn_exp2f(p[i] - m2);
            p[i] = e;
            rs += e;
        }
        rs += __shfl_xor(rs, 16);
        rs += __shfl_xor(rs, 32);
        lsum += rs;

        // ---- pack P to bf16 (k-consecutive per lane) and write per-wave LDS
        #pragma unroll
        for (int ct = 0; ct < 4; ++ct) {
            unsigned lo, hi;
            asm("v_cvt_pk_bf16_f32 %0, %1, %2" : "=v"(lo) : "v"(p[ct * 4 + 0]), "v"(p[ct * 4 + 1]));
            asm("v_cvt_pk_bf16_f32 %0, %1, %2" : "=v"(hi) : "v"(p[ct * 4 + 2]), "v"(p[ct * 4 + 3]));
            *reinterpret_cast<uint2*>(&Pl[wv][l15][ct * 16 + l4 * 4]) = make_uint2(lo, hi);
        }

        // ---- PV: A = P (LDS frags), B = V^T (direct global frags)
        const bf16x8 pf0 = *reinterpret_cast<const bf16x8*>(&Pl[wv][l15][l4 * 8]);
        const bf16x8 pf1 = *reinterpret_cast<const bf16x8*>(&Pl[wv][l15][32 + l4 * 8]);
        const unsigned short* Vt = Vb + kt * 64;
        #pragma unroll
        for (int dt = 0; dt < 4; ++dt) {
            const bf16x8 vf0 = *reinterpret_cast<const bf16x8*>(Vt + (size_t)(dt * 16 + l15) * Ss + l4 * 8);
            const bf16x8 vf1 = *reinterpret_cast<const bf16x8*>(Vt + (size_t)(dt * 16 + l15) * Ss + 32 + l4 * 8);
            oacc[dt] = __builtin_amdgcn_mfma_f32_16x16x32_bf16(pf0, vf0, oacc[dt], 0, 0, 0);
            oacc[dt] = __builtin_amdgcn_mfma_f32_16x16x32_bf16(pf1, vf1, oacc[dt], 0, 0, 0);
        }
    }

    // ---- epilogue: normalize (stats live at lane l15 == q-row; shuffle to row layout)
    #pragma unroll
    for (int r = 0; r < 4; ++r) {
        const float li = __shfl(lsum, l4 * 4 + r);
        const float inv = 1.f / li;
        const int s = qt * 64 + wv * 16 + l4 * 4 + r;
        float* op = out + ((size_t)b * Ss + s) * Dd + h * DH;
        #pragma unroll
        for (int dt = 0; dt < 4; ++dt)
            op[dt * 16 + l15] = oacc[dt][r] * inv;
    }
}

// ---------------- kernel 5: loss = LMBDA * H * sum(mask) ----------------
__global__ __launch_bounds__(256) void k_loss(const float* __restrict__ mask,
                                              float* __restrict__ out) {
    __shared__ float red[4];
    float s = 0.f;
    for (int i = threadIdx.x; i < Bb * Ss; i += 256) s += mask[i];
    #pragma unroll
    for (int d = 1; d < 64; d <<= 1) s += __shfl_xor(s, d);
    const int lane = threadIdx.x & 63, wv = threadIdx.x >> 6;
    if (lane == 0) red[wv] = s;
    __syncthreads();
    if (threadIdx.x == 0)
        out[0] = 0.01f * 12.f * (red[0] + red[1] + red[2] + red[3]);
}

extern "C" void kernel_launch(void* const* d_in, const int* in_sizes, int n_in,
                              void* d_out, int out_size, void* d_ws, size_t ws_size,
                              hipStream_t stream) {
    const float* hs   = (const float*)d_in[0];
    const float* mask = (const float*)d_in[1];
    const float* Wq   = (const float*)d_in[2];
    const float* bq   = (const float*)d_in[3];
    const float* Wk   = (const float*)d_in[4];
    const float* bk   = (const float*)d_in[5];
    const float* Wv   = (const float*)d_in[6];
    const float* bv   = (const float*)d_in[7];
    float* out = (float*)d_out;

    uint8_t* ws = (uint8_t*)d_ws;
    unsigned short* hb = (unsigned short*)(ws);
    unsigned short* Wt = (unsigned short*)(ws + 12582912);
    unsigned short* Qw = (unsigned short*)(ws + 16121856);
    unsigned short* Kw = (unsigned short*)(ws + 28704768);
    unsigned short* Vw = (unsigned short*)(ws + 41287680);

    hipLaunchKernelGGL(k_cvt,  dim3(6144),      dim3(256), 0, stream, hs, hb);
    hipLaunchKernelGGL(k_twt,  dim3(24, 24, 3), dim3(256), 0, stream, Wq, Wk, Wv, Wt);
    hipLaunchKernelGGL(k_qkv,  dim3(64, 6, 3),  dim3(256), 0, stream, hb, Wt, bq, bk, bv, Qw, Kw, Vw);
    hipLaunchKernelGGL(k_attn, dim3(16, 96),    dim3(256), 0, stream, Qw, Kw, Vw, mask, out);
    hipLaunchKernelGGL(k_loss, dim3(1),         dim3(256), 0, stream, mask, out + 6291456);
}

// Round 5
// 211.026 us; speedup vs baseline: 1.5565x; 1.5565x over previous
//
#include <hip/hip_runtime.h>
#include <hip/hip_bf16.h>
#include <stdint.h>

#define Bb 8
#define Ss 1024
#define Dd 768
#define Hh 12
#define DH 64

typedef __attribute__((ext_vector_type(8))) short bf16x8;
typedef __attribute__((ext_vector_type(4))) float f32x4;

static __device__ __forceinline__ unsigned short f2b(float x) {
    union { float f; unsigned u; } v; v.f = x;
    unsigned r = v.u + 0x7FFFu + ((v.u >> 16) & 1u);
    return (unsigned short)(r >> 16);
}

static __device__ __forceinline__ void gll16(const void* g, void* l) {
    __builtin_amdgcn_global_load_lds((const __attribute__((address_space(1))) void*)g,
                                     (__attribute__((address_space(3))) void*)l,
                                     16, 0, 0);
}

// ---------------- kernel 1: hidden f32 -> bf16 ----------------
__global__ __launch_bounds__(256) void k_cvt(const float* __restrict__ in,
                                             unsigned short* __restrict__ out) {
    int i = (blockIdx.x * 256 + threadIdx.x) * 4;
    const float4 v = *reinterpret_cast<const float4*>(in + i);
    ushort4 o;
    o.x = f2b(v.x); o.y = f2b(v.y); o.z = f2b(v.z); o.w = f2b(v.w);
    *reinterpret_cast<ushort4*>(out + i) = o;
}

// ---------------- kernel 2: W[k][n] f32 -> Wt[w][n][k] bf16 ----------------
__global__ __launch_bounds__(256) void k_twt(const float* __restrict__ Wq,
                                             const float* __restrict__ Wk,
                                             const float* __restrict__ Wv,
                                             unsigned short* __restrict__ Wt) {
    __shared__ float tile[32][33];
    const int w = blockIdx.z;
    const float* W = (w == 0) ? Wq : (w == 1) ? Wk : Wv;
    const int k0 = blockIdx.x * 32, n0 = blockIdx.y * 32;
    const int c = threadIdx.x & 31, r0 = threadIdx.x >> 5;
    #pragma unroll
    for (int i = 0; i < 4; ++i)
        tile[r0 + i * 8][c] = W[(size_t)(k0 + r0 + i * 8) * Dd + n0 + c];
    __syncthreads();
    unsigned short* o = Wt + (size_t)w * Dd * Dd;
    #pragma unroll
    for (int i = 0; i < 4; ++i)
        o[(size_t)(n0 + r0 + i * 8) * Dd + k0 + c] = f2b(tile[c][r0 + i * 8]);
}

// ---------------- kernel 3: QKV GEMM (m97 structure) ----------------
__global__ __launch_bounds__(256) void k_qkv(
    const unsigned short* __restrict__ hb,   // [8192][768] bf16
    const unsigned short* __restrict__ Wt,   // [3][768][768] bf16 (n,k)
    const float* __restrict__ bq, const float* __restrict__ bk, const float* __restrict__ bv,
    unsigned short* __restrict__ Qo, unsigned short* __restrict__ Ko,
    unsigned short* __restrict__ Vo) {
    __shared__ __align__(16) unsigned short Al[128 * 32];
    __shared__ __align__(16) unsigned short Bl[128 * 32];
    const int m0 = blockIdx.x * 128;
    const int n0 = blockIdx.y * 128;
    const int w  = blockIdx.z;
    const int tid = threadIdx.x, lane = tid & 63, wv = tid >> 6;
    const int l15 = lane & 15, l4 = lane >> 4;
    const int wm = (wv >> 1) * 64, wn = (wv & 1) * 64;
    const unsigned short* Wb = Wt + (size_t)w * Dd * Dd;

    f32x4 acc[4][4];
    #pragma unroll
    for (int i = 0; i < 4; ++i)
        #pragma unroll
        for (int j = 0; j < 4; ++j)
            acc[i][j] = f32x4{0.f, 0.f, 0.f, 0.f};

    const int ldr = lane >> 2;
    const int ldc = (lane & 3) * 8;

    for (int kt = 0; kt < Dd / 32; ++kt) {
        const int k0 = kt * 32;
        #pragma unroll
        for (int i = 0; i < 2; ++i) {
            const int c = wv * 2 + i;
            gll16(hb + (size_t)(m0 + c * 16 + ldr) * Dd + k0 + ldc, Al + c * 512);
            gll16(Wb + (size_t)(n0 + c * 16 + ldr) * Dd + k0 + ldc, Bl + c * 512);
        }
        __syncthreads();
        bf16x8 af[4], bfr[4];
        #pragma unroll
        for (int i = 0; i < 4; ++i) {
            af[i]  = *reinterpret_cast<const bf16x8*>(Al + (wm + i * 16 + l15) * 32 + l4 * 8);
            bfr[i] = *reinterpret_cast<const bf16x8*>(Bl + (wn + i * 16 + l15) * 32 + l4 * 8);
        }
        #pragma unroll
        for (int i = 0; i < 4; ++i)
            #pragma unroll
            for (int j = 0; j < 4; ++j)
                acc[i][j] = __builtin_amdgcn_mfma_f32_16x16x32_bf16(af[i], bfr[j], acc[i][j], 0, 0, 0);
        __syncthreads();
    }

    const float* bias = (w == 0) ? bq : (w == 1) ? bk : bv;
    if (w < 2) {
        unsigned short* O = (w == 0) ? Qo : Ko;
        #pragma unroll
        for (int j = 0; j < 4; ++j) {
            const int n = n0 + wn + j * 16 + l15;
            const float bs = bias[n];
            const int hh = n >> 6, d = n & 63;
            #pragma unroll
            for (int i = 0; i < 4; ++i) {
                const int mb = m0 + wm + i * 16 + l4 * 4;
                #pragma unroll
                for (int r = 0; r < 4; ++r) {
                    const int m = mb + r;
                    const int b = m >> 10, s = m & 1023;
                    O[(((size_t)b * Hh + hh) * Ss + s) * DH + d] = f2b(acc[i][j][r] + bs);
                }
            }
        }
    } else {
        #pragma unroll
        for (int j = 0; j < 4; ++j) {
            const int n = n0 + wn + j * 16 + l15;
            const float bs = bias[n];
            const int hh = n >> 6, d = n & 63;
            #pragma unroll
            for (int i = 0; i < 4; ++i) {
                const int m = m0 + wm + i * 16 + l4 * 4;
                const int b = m >> 10, s = m & 1023;
                ushort4 o;
                o.x = f2b(acc[i][j][0] + bs);
                o.y = f2b(acc[i][j][1] + bs);
                o.z = f2b(acc[i][j][2] + bs);
                o.w = f2b(acc[i][j][3] + bs);
                *reinterpret_cast<ushort4*>(Vo + (((size_t)b * Hh + hh) * DH + d) * Ss + s) = o;
            }
        }
    }
}

// ---------------- kernel 4: flash attention ----------------
// LDS-staged K/V (once per block, shared by 4 waves) with XOR-swizzle via
// pre-swizzled GLOBAL source (rule #21: linear gll dest + swizzled src + swizzled read).
// Swapped QK^T (mfma(K,Q)) -> q-row lane-local softmax; exp2 domain; defer-max.
__global__ __launch_bounds__(256) void k_attn(
    const unsigned short* __restrict__ Q,   // [96][1024][64]
    const unsigned short* __restrict__ K,   // [96][1024][64]
    const unsigned short* __restrict__ VT,  // [96][64][1024]
    const float* __restrict__ mask,         // [8][1024]
    float* __restrict__ out) {              // [8][1024][768]
    __shared__ __align__(16) unsigned short Kl[64 * 64];   // swizzled [row][slot^row&7]
    __shared__ __align__(16) unsigned short Vl[64 * 64];   // swizzled
    __shared__ __align__(16) unsigned short Pl[4][16][72];
    __shared__ __align__(16) float Ml[1024];               // mask * log2e

    // XCD-aware bijective chunk swizzle: XCD x owns 12 whole heads (3MB K/V < 4MB L2)
    const int bid = blockIdx.x;                 // 0..1535
    const int wg  = (bid & 7) * 192 + (bid >> 3);
    const int bh  = wg >> 4;                    // 0..95 (16 consecutive wg share a head)
    const int qt  = wg & 15;
    const int b = bh / Hh, h = bh % Hh;
    const int tid = threadIdx.x, lane = tid & 63, wv = tid >> 6;
    const int l15 = lane & 15, l4 = lane >> 4;
    const int q0 = qt * 64 + wv * 16;

    const unsigned short* Qb = Q + (size_t)bh * Ss * DH;
    const unsigned short* Kb = K + (size_t)bh * Ss * DH;
    const unsigned short* Vb = VT + (size_t)bh * DH * Ss;
    const float* mb = mask + (size_t)b * Ss;

    {   // stage mask row, pre-scaled to log2 domain
        const float4 mv = *reinterpret_cast<const float4*>(mb + tid * 4);
        float4 ms;
        ms.x = mv.x * 1.44269504f; ms.y = mv.y * 1.44269504f;
        ms.z = mv.z * 1.44269504f; ms.w = mv.w * 1.44269504f;
        *reinterpret_cast<float4*>(&Ml[tid * 4]) = ms;
    }

    const bf16x8 qf0 = *reinterpret_cast<const bf16x8*>(Qb + (q0 + l15) * DH + l4 * 8);
    const bf16x8 qf1 = *reinterpret_cast<const bf16x8*>(Qb + (q0 + l15) * DH + 32 + l4 * 8);

    float m2 = -3.0e38f, lsum = 0.f;   // stats for q-row = l15 (log2 domain)
    f32x4 oacc[4];
    #pragma unroll
    for (int dt = 0; dt < 4; ++dt) oacc[dt] = f32x4{0.f, 0.f, 0.f, 0.f};

    const float C1 = 0.125f * 1.44269504f;

    // staging lane decomposition: each gll covers 8 rows x 128B
    const int srow = lane >> 3;              // 0..7 row within 8-row stripe
    const int sslt = lane & 7;               // 16B slot within row

    for (int kt = 0; kt < Ss / 64; ++kt) {
        {   // ---- stage K,V tiles (linear LDS dest, pre-swizzled global src)
            const int r0 = wv * 16;
            #pragma unroll
            for (int i = 0; i < 2; ++i) {
                const int rK = r0 + i * 8 + srow;
                const int gsK = sslt ^ (rK & 7);
                gll16(Kb + (size_t)(kt * 64 + rK) * DH + gsK * 8, Kl + (r0 + i * 8) * 64);
                gll16(Vb + (size_t)rK * Ss + kt * 64 + gsK * 8,   Vl + (r0 + i * 8) * 64);
            }
        }
        __syncthreads();

        // ---- QK^T (swapped): sc[ct][r] = S[k = kt*64+ct*16+l4*4+r][q = q0+l15]
        f32x4 sc[4];
        #pragma unroll
        for (int ct = 0; ct < 4; ++ct) {
            const int kr = ct * 16 + l15;
            const int sw = kr & 7;
            const bf16x8 kf0 = *reinterpret_cast<const bf16x8*>(Kl + kr * 64 + ((l4 ^ sw) * 8));
            const bf16x8 kf1 = *reinterpret_cast<const bf16x8*>(Kl + kr * 64 + (((l4 + 4) ^ sw) * 8));
            f32x4 a = f32x4{0.f, 0.f, 0.f, 0.f};
            a = __builtin_amdgcn_mfma_f32_16x16x32_bf16(kf0, qf0, a, 0, 0, 0);
            a = __builtin_amdgcn_mfma_f32_16x16x32_bf16(kf1, qf1, a, 0, 0, 0);
            sc[ct] = a;
        }

        // ---- mask tile (broadcast LDS reads)
        float4 mk[4];
        #pragma unroll
        for (int ct = 0; ct < 4; ++ct)
            mk[ct] = *reinterpret_cast<const float4*>(&Ml[kt * 64 + ct * 16 + l4 * 4]);

        // ---- scores -> p (log2 domain), row max
        float p[16];
        float pmax = -3.0e38f;
        const bool dk = (kt == qt);
        #pragma unroll
        for (int ct = 0; ct < 4; ++ct) {
            const float* mkp = reinterpret_cast<const float*>(&mk[ct]);
            #pragma unroll
            for (int r = 0; r < 4; ++r) {
                float t = fmaf(sc[ct][r], C1, mkp[r]);
                if (dk && (ct * 16 + l4 * 4 + r) == (wv * 16 + l15)) t = mkp[r];  // blind spot
                p[ct * 4 + r] = t;
                pmax = fmaxf(pmax, t);
            }
        }
        pmax = fmaxf(pmax, __shfl_xor(pmax, 16));
        pmax = fmaxf(pmax, __shfl_xor(pmax, 32));

        // ---- defer-max (T13)
        if (__any(pmax > m2 + 10.f)) {
            const float mnew = fmaxf(m2, pmax);
            const float alpha = __builtin_amdgcn_exp2f(m2 - mnew);
            m2 = mnew;
            lsum *= alpha;
            float ar[4];
            #pragma unroll
            for (int r = 0; r < 4; ++r) ar[r] = __shfl(alpha, l4 * 4 + r);
            #pragma unroll
            for (int dt = 0; dt < 4; ++dt)
                #pragma unroll
                for (int r = 0; r < 4; ++r) oacc[dt][r] *= ar[r];
        }

        // ---- exp2 + row sum
        float rs = 0.f;
        #pragma unroll
        for (int i = 0; i < 16; ++i) {
            const float e = __builtin_amdgcn_exp2f(p[i] - m2);
            p[i] = e;
            rs += e;
        }
        rs += __shfl_xor(rs, 16);
        rs += __shfl_xor(rs, 32);
        lsum += rs;

        // ---- pack P to bf16 and write per-wave LDS
        #pragma unroll
        for (int ct = 0; ct < 4; ++ct) {
            unsigned lo, hi;
            asm("v_cvt_pk_bf16_f32 %0, %1, %2" : "=v"(lo) : "v"(p[ct * 4 + 0]), "v"(p[ct * 4 + 1]));
            asm("v_cvt_pk_bf16_f32 %0, %1, %2" : "=v"(hi) : "v"(p[ct * 4 + 2]), "v"(p[ct * 4 + 3]));
            *reinterpret_cast<uint2*>(&Pl[wv][l15][ct * 16 + l4 * 4]) = make_uint2(lo, hi);
        }

        // ---- PV: A = P frags, B = V^T frags from swizzled LDS
        const bf16x8 pf0 = *reinterpret_cast<const bf16x8*>(&Pl[wv][l15][l4 * 8]);
        const bf16x8 pf1 = *reinterpret_cast<const bf16x8*>(&Pl[wv][l15][32 + l4 * 8]);
        #pragma unroll
        for (int dt = 0; dt < 4; ++dt) {
            const int vr = dt * 16 + l15;
            const int sv = vr & 7;
            const bf16x8 vf0 = *reinterpret_cast<const bf16x8*>(Vl + vr * 64 + ((l4 ^ sv) * 8));
            const bf16x8 vf1 = *reinterpret_cast<const bf16x8*>(Vl + vr * 64 + (((l4 + 4) ^ sv) * 8));
            oacc[dt] = __builtin_amdgcn_mfma_f32_16x16x32_bf16(pf0, vf0, oacc[dt], 0, 0, 0);
            oacc[dt] = __builtin_amdgcn_mfma_f32_16x16x32_bf16(pf1, vf1, oacc[dt], 0, 0, 0);
        }
        __syncthreads();   // protect Kl/Vl before next-iter staging
    }

    // ---- epilogue: normalize
    #pragma unroll
    for (int r = 0; r < 4; ++r) {
        const float li = __shfl(lsum, l4 * 4 + r);
        const float inv = 1.f / li;
        const int s = qt * 64 + wv * 16 + l4 * 4 + r;
        float* op = out + ((size_t)b * Ss + s) * Dd + h * DH;
        #pragma unroll
        for (int dt = 0; dt < 4; ++dt)
            op[dt * 16 + l15] = oacc[dt][r] * inv;
    }
}

// ---------------- kernel 5: loss = LMBDA * H * sum(mask) ----------------
__global__ __launch_bounds__(256) void k_loss(const float* __restrict__ mask,
                                              float* __restrict__ out) {
    __shared__ float red[4];
    float s = 0.f;
    for (int i = threadIdx.x; i < Bb * Ss; i += 256) s += mask[i];
    #pragma unroll
    for (int d = 1; d < 64; d <<= 1) s += __shfl_xor(s, d);
    const int lane = threadIdx.x & 63, wv = threadIdx.x >> 6;
    if (lane == 0) red[wv] = s;
    __syncthreads();
    if (threadIdx.x == 0)
        out[0] = 0.01f * 12.f * (red[0] + red[1] + red[2] + red[3]);
}

extern "C" void kernel_launch(void* const* d_in, const int* in_sizes, int n_in,
                              void* d_out, int out_size, void* d_ws, size_t ws_size,
                              hipStream_t stream) {
    const float* hs   = (const float*)d_in[0];
    const float* mask = (const float*)d_in[1];
    const float* Wq   = (const float*)d_in[2];
    const float* bq   = (const float*)d_in[3];
    const float* Wk   = (const float*)d_in[4];
    const float* bk   = (const float*)d_in[5];
    const float* Wv   = (const float*)d_in[6];
    const float* bv   = (const float*)d_in[7];
    float* out = (float*)d_out;

    uint8_t* ws = (uint8_t*)d_ws;
    unsigned short* hb = (unsigned short*)(ws);
    unsigned short* Wt = (unsigned short*)(ws + 12582912);
    unsigned short* Qw = (unsigned short*)(ws + 16121856);
    unsigned short* Kw = (unsigned short*)(ws + 28704768);
    unsigned short* Vw = (unsigned short*)(ws + 41287680);

    hipLaunchKernelGGL(k_cvt,  dim3(6144),      dim3(256), 0, stream, hs, hb);
    hipLaunchKernelGGL(k_twt,  dim3(24, 24, 3), dim3(256), 0, stream, Wq, Wk, Wv, Wt);
    hipLaunchKernelGGL(k_qkv,  dim3(64, 6, 3),  dim3(256), 0, stream, hb, Wt, bq, bk, bv, Qw, Kw, Vw);
    hipLaunchKernelGGL(k_attn, dim3(1536),      dim3(256), 0, stream, Qw, Kw, Vw, mask, out);
    hipLaunchKernelGGL(k_loss, dim3(1),         dim3(256), 0, stream, mask, out + 6291456);
}